// Round 7
// baseline (1599.317 us; speedup 1.0000x reference)
//
#include <hip/hip_runtime.h>
#include <hip/hip_bf16.h>

#define NB 64
#define T1 3136
#define T2 784
#define T3 196
#define D1 147
#define D2 576

__device__ __forceinline__ float waveReduceSum(float v) {
#pragma unroll
    for (int off = 32; off > 0; off >>= 1) v += __shfl_down(v, off, 64);
    return __shfl(v, 0, 64);
}

// ---------------------------------------------------------------------------
// front1: 32 tokens/block, 256 threads. unfold(7,4,2) + LN + kqv + prm_exp.
// Thread owns 3 cols {c,c+64,c+128} x 8 tokens. rf rows register-resident.
// ---------------------------------------------------------------------------
__global__ __launch_bounds__(256) void front1(
    const float* __restrict__ x,
    const float* __restrict__ kqv_w,   // (147,192)
    const float* __restrict__ kqv_b,   // (192)
    const float* __restrict__ ln_g, const float* __restrict__ ln_b,  // (147)
    const float* __restrict__ rf,      // (32,64)
    float* __restrict__ kp, float* __restrict__ qp,   // (B*T1,32)
    float* __restrict__ v_out)                        // (B*T1,64)
{
    const int tok0 = blockIdx.x * 32;
    const int b = tok0 / T1;
    const int tbase = tok0 % T1;   // T1 % 32 == 0
    const int tid = threadIdx.x;
    const int c = tid & 63, tg = tid >> 6;   // col base, token group
    const int lane = tid & 63;

    __shared__ __align__(16) float smem[D1 * 36];   // ft[d][m] pad36; kq aliases
    __shared__ float ps_sum[256], ps_sq[256];
    __shared__ float mu_s[32], rs_s[32];
    __shared__ float xd_s[64];                       // [half][m]

    float* ft  = smem;
    float* kqs = smem;                               // [2][32][64] after matvec

    // rf row (tid&31) -> registers (slot stride 256 keeps mrf==tid&31)
    float4 rfr[16];
    { const float* rp = rf + (size_t)(tid & 31) * 64;
#pragma unroll
      for (int g = 0; g < 16; ++g) rfr[g] = *(const float4*)(rp + 4 * g); }

    // unfold gather -> ft[d*36+m]
    for (int idx = tid; idx < D1 * 32; idx += 256) {
        const int m = idx & 31, d = idx >> 5;
        const int t = tbase + m;
        const int py = t / 56, px = t % 56;
        const int cc = d / 49, r = d % 49, ki = r / 7, kj = r % 7;
        const int iy = py * 4 - 2 + ki, ix = px * 4 - 2 + kj;
        float val = 0.f;
        if (iy >= 0 && iy < 224 && ix >= 0 && ix < 224)
            val = x[((b * 3 + cc) * 224 + iy) * 224 + ix];
        ft[d * 36 + m] = val;
    }
    __syncthreads();

    // LN partials: m = tid&31, j = tid>>5 (0..7)
    { const int m = tid & 31, j = tid >> 5;
      float s = 0.f, s2 = 0.f;
      for (int d = j; d < D1; d += 8) { const float u = ft[d*36+m]; s += u; s2 += u*u; }
      ps_sum[tid] = s; ps_sq[tid] = s2; }
    __syncthreads();
    if (tid < 32) {
        float s = 0.f, s2 = 0.f;
        for (int j = 0; j < 8; ++j) { s += ps_sum[j*32+tid]; s2 += ps_sq[j*32+tid]; }
        const float mu = s * (1.f / D1);
        const float var = s2 * (1.f / D1) - mu * mu;
        mu_s[tid] = mu; rs_s[tid] = rsqrtf(var + 1e-5f);
    }
    __syncthreads();
    for (int idx = tid; idx < D1 * 32; idx += 256) {
        const int m = idx & 31, d = idx >> 5;
        ft[d*36+m] = (ft[d*36+m] - mu_s[m]) * rs_s[m] * ln_g[d] + ln_b[d];
    }
    __syncthreads();

    // matvec: 3 cols x 8 tokens per thread
    float acc[3][8];
    { const float b0 = kqv_b[c], b1 = kqv_b[64 + c], b2 = kqv_b[128 + c];
#pragma unroll
      for (int m = 0; m < 8; ++m) { acc[0][m] = b0; acc[1][m] = b1; acc[2][m] = b2; } }
#pragma unroll 2
    for (int d = 0; d < D1; ++d) {
        const float w0 = kqv_w[d * 192 + c];
        const float w1 = kqv_w[d * 192 + c + 64];
        const float w2 = kqv_w[d * 192 + c + 128];
        const float4 f0 = *(const float4*)&ft[d * 36 + 8 * tg];
        const float4 f1 = *(const float4*)&ft[d * 36 + 8 * tg + 4];
        acc[0][0] += f0.x*w0; acc[0][1] += f0.y*w0; acc[0][2] += f0.z*w0; acc[0][3] += f0.w*w0;
        acc[0][4] += f1.x*w0; acc[0][5] += f1.y*w0; acc[0][6] += f1.z*w0; acc[0][7] += f1.w*w0;
        acc[1][0] += f0.x*w1; acc[1][1] += f0.y*w1; acc[1][2] += f0.z*w1; acc[1][3] += f0.w*w1;
        acc[1][4] += f1.x*w1; acc[1][5] += f1.y*w1; acc[1][6] += f1.z*w1; acc[1][7] += f1.w*w1;
        acc[2][0] += f0.x*w2; acc[2][1] += f0.y*w2; acc[2][2] += f0.z*w2; acc[2][3] += f0.w*w2;
        acc[2][4] += f1.x*w2; acc[2][5] += f1.y*w2; acc[2][6] += f1.z*w2; acc[2][7] += f1.w*w2;
    }
    __syncthreads();   // all ft reads done before kqs aliases it

    // stores: v to global; k,q to LDS (pad 64, lane-consecutive writes)
#pragma unroll
    for (int m = 0; m < 8; ++m)
        v_out[(size_t)(tok0 + 8 * tg + m) * 64 + c] = acc[2][m];
#pragma unroll
    for (int m = 0; m < 8; ++m) {
        kqs[(0 * 32 + 8 * tg + m) * 64 + c] = acc[0][m];
        kqs[(1 * 32 + 8 * tg + m) * 64 + c] = acc[1][m];
    }
#pragma unroll
    for (int m = 0; m < 8; ++m) {
        const float sk = waveReduceSum(acc[0][m] * acc[0][m]);
        const float sq = waveReduceSum(acc[1][m] * acc[1][m]);
        if (lane == 0) { xd_s[8 * tg + m] = 0.5f * sk; xd_s[32 + 8 * tg + m] = 0.5f * sq; }
    }
    __syncthreads();

    // prm_exp: 2048 slots; mrf = tid&31 constant; kq rows broadcast-read
    for (int slot = tid; slot < 2048; slot += 256) {
        const int half = slot >> 10, rem = slot & 1023;
        const int m = rem >> 5, mrf = slot & 31;
        const float4* k4 = (const float4*)&kqs[(half * 32 + m) * 64];
        float a = 0.f;
#pragma unroll
        for (int g = 0; g < 16; ++g) {
            const float4 kv = k4[g];
            a += rfr[g].x*kv.x + rfr[g].y*kv.y + rfr[g].z*kv.z + rfr[g].w*kv.w;
        }
        const float p = expf(a - xd_s[half * 32 + m]) * 0.1767766952966369f;
        (half ? qp : kp)[(size_t)(tok0 + m) * 32 + mrf] = p;
    }
}

// ---------------------------------------------------------------------------
// front2: 16 tokens/block, 128 threads. unfold(3,2,1) + LN + kqv + prm_exp.
// Thread owns 3 cols x 8 tokens. LDS ~47KB -> 3 blocks/CU.
// ---------------------------------------------------------------------------
__global__ __launch_bounds__(128) void front2(
    const float* __restrict__ src,     // o1 (B*T1,64)
    const float* __restrict__ kqv_w,   // (576,192)
    const float* __restrict__ kqv_b,
    const float* __restrict__ ln_g, const float* __restrict__ ln_b,  // (576)
    const float* __restrict__ rf,
    float* __restrict__ kp, float* __restrict__ qp,   // (B*T2,32)
    float* __restrict__ v_out)                        // (B*T2,64)
{
    const int tok0 = blockIdx.x * 16;
    const int b = tok0 / T2;
    const int tbase = tok0 % T2;   // T2 % 16 == 0
    const int tid = threadIdx.x;
    const int c = tid & 63, tg = tid >> 6;   // tg in [0,2)
    const int lane = tid & 63;

    __shared__ __align__(16) float smem[D2 * 20];   // ft; kq aliases
    __shared__ float ps_sum[128], ps_sq[128];
    __shared__ float mu_s[16], rs_s[16];
    __shared__ float xd_s[32];

    float* ft  = smem;
    float* kqs = smem;    // [2][16][64]

    float4 rfr[16];
    { const float* rp = rf + (size_t)(tid & 31) * 64;
#pragma unroll
      for (int g = 0; g < 16; ++g) rfr[g] = *(const float4*)(rp + 4 * g); }

    // gather: lanes own channel c (coalesced src reads)
    for (int u = tg; u < 16 * 9; u += 2) {
        const int m = u / 9, r = u % 9;
        const int t = tbase + m;
        const int py = t / 28, px = t % 28;
        const int ki = r / 3, kj = r % 3;
        const int iy = py * 2 - 1 + ki, ix = px * 2 - 1 + kj;
        float val = 0.f;
        if (iy >= 0 && iy < 56 && ix >= 0 && ix < 56)
            val = src[(size_t)(b * T1 + iy * 56 + ix) * 64 + c];
        ft[(c * 9 + r) * 20 + m] = val;
    }
    __syncthreads();

    { const int m = tid & 15, j = tid >> 4;   // j 0..7
      float s = 0.f, s2 = 0.f;
      for (int d = j; d < D2; d += 8) { const float u = ft[d*20+m]; s += u; s2 += u*u; }
      ps_sum[tid] = s; ps_sq[tid] = s2; }
    __syncthreads();
    if (tid < 16) {
        float s = 0.f, s2 = 0.f;
        for (int j = 0; j < 8; ++j) { s += ps_sum[j*16+tid]; s2 += ps_sq[j*16+tid]; }
        const float mu = s * (1.f / D2);
        const float var = s2 * (1.f / D2) - mu * mu;
        mu_s[tid] = mu; rs_s[tid] = rsqrtf(var + 1e-5f);
    }
    __syncthreads();
    for (int idx = tid; idx < D2 * 16; idx += 128) {
        const int m = idx & 15, d = idx >> 4;
        ft[d*20+m] = (ft[d*20+m] - mu_s[m]) * rs_s[m] * ln_g[d] + ln_b[d];
    }
    __syncthreads();

    float acc[3][8];
    { const float b0 = kqv_b[c], b1 = kqv_b[64 + c], b2 = kqv_b[128 + c];
#pragma unroll
      for (int m = 0; m < 8; ++m) { acc[0][m] = b0; acc[1][m] = b1; acc[2][m] = b2; } }
#pragma unroll 2
    for (int d = 0; d < D2; ++d) {
        const float w0 = kqv_w[d * 192 + c];
        const float w1 = kqv_w[d * 192 + c + 64];
        const float w2 = kqv_w[d * 192 + c + 128];
        const float4 f0 = *(const float4*)&ft[d * 20 + 8 * tg];
        const float4 f1 = *(const float4*)&ft[d * 20 + 8 * tg + 4];
        acc[0][0] += f0.x*w0; acc[0][1] += f0.y*w0; acc[0][2] += f0.z*w0; acc[0][3] += f0.w*w0;
        acc[0][4] += f1.x*w0; acc[0][5] += f1.y*w0; acc[0][6] += f1.z*w0; acc[0][7] += f1.w*w0;
        acc[1][0] += f0.x*w1; acc[1][1] += f0.y*w1; acc[1][2] += f0.z*w1; acc[1][3] += f0.w*w1;
        acc[1][4] += f1.x*w1; acc[1][5] += f1.y*w1; acc[1][6] += f1.z*w1; acc[1][7] += f1.w*w1;
        acc[2][0] += f0.x*w2; acc[2][1] += f0.y*w2; acc[2][2] += f0.z*w2; acc[2][3] += f0.w*w2;
        acc[2][4] += f1.x*w2; acc[2][5] += f1.y*w2; acc[2][6] += f1.z*w2; acc[2][7] += f1.w*w2;
    }
    __syncthreads();

#pragma unroll
    for (int m = 0; m < 8; ++m)
        v_out[(size_t)(tok0 + 8 * tg + m) * 64 + c] = acc[2][m];
#pragma unroll
    for (int m = 0; m < 8; ++m) {
        kqs[(0 * 16 + 8 * tg + m) * 64 + c] = acc[0][m];
        kqs[(1 * 16 + 8 * tg + m) * 64 + c] = acc[1][m];
    }
#pragma unroll
    for (int m = 0; m < 8; ++m) {
        const float sk = waveReduceSum(acc[0][m] * acc[0][m]);
        const float sq = waveReduceSum(acc[1][m] * acc[1][m]);
        if (lane == 0) { xd_s[8 * tg + m] = 0.5f * sk; xd_s[16 + 8 * tg + m] = 0.5f * sq; }
    }
    __syncthreads();

    for (int slot = tid; slot < 1024; slot += 128) {
        const int half = slot >> 9, rem = slot & 511;
        const int m = rem >> 5, mrf = slot & 31;
        const float4* k4 = (const float4*)&kqs[(half * 16 + m) * 64];
        float a = 0.f;
#pragma unroll
        for (int g = 0; g < 16; ++g) {
            const float4 kv = k4[g];
            a += rfr[g].x*kv.x + rfr[g].y*kv.y + rfr[g].z*kv.z + rfr[g].w*kv.w;
        }
        const float p = expf(a - xd_s[half * 16 + m]) * 0.1767766952966369f;
        (half ? qp : kp)[(size_t)(tok0 + m) * 32 + mrf] = p;
    }
}

// ---------------------------------------------------------------------------
// reduce_kv, split S-ways over T with atomics (ksum/kptv pre-zeroed)
// ---------------------------------------------------------------------------
template <int T, int S>
__global__ __launch_bounds__(256) void reduce_kv(
    const float* __restrict__ kp, const float* __restrict__ v,
    float* __restrict__ ksum, float* __restrict__ kptv)
{
    const int b = blockIdx.x / S, s = blockIdx.x % S;
    const int chunk = T / S;
    const int tid = threadIdx.x;
    __shared__ float kp_s[8][32];
    __shared__ float v_s[8][64];
    float acc[8] = {0.f, 0.f, 0.f, 0.f, 0.f, 0.f, 0.f, 0.f};
    float ks = 0.f;
    const int n = tid >> 2;
    const int mb = (tid & 3) * 8;
    const float* kpb = kp + (size_t)b * T * 32;
    const float* vb  = v  + (size_t)b * T * 64;

    for (int t0 = s * chunk; t0 < (s + 1) * chunk; t0 += 8) {
        kp_s[tid >> 5][tid & 31] = kpb[(t0 + (tid >> 5)) * 32 + (tid & 31)];
        {
            const int i0 = tid * 2, i1 = tid * 2 + 1;
            v_s[i0 >> 6][i0 & 63] = vb[(t0 + (i0 >> 6)) * 64 + (i0 & 63)];
            v_s[i1 >> 6][i1 & 63] = vb[(t0 + (i1 >> 6)) * 64 + (i1 & 63)];
        }
        __syncthreads();
#pragma unroll
        for (int tt = 0; tt < 8; ++tt) {
            const float vv = v_s[tt][n];
#pragma unroll
            for (int i = 0; i < 8; ++i) acc[i] += vv * kp_s[tt][mb + i];
        }
        if (tid < 32) {
#pragma unroll
            for (int tt = 0; tt < 8; ++tt) ks += kp_s[tt][tid];
        }
        __syncthreads();
    }
#pragma unroll
    for (int i = 0; i < 8; ++i) atomicAdd(&kptv[(b * 64 + n) * 32 + mb + i], acc[i]);
    if (tid < 32) atomicAdd(&ksum[b * 32 + tid], ks);
}

// ---------------------------------------------------------------------------
// epilogue: 128 threads = two independent 16-token tiles. Each sub-tile
// computes its own batch index and loads its own ksum (T2 % 32 != 0: a block
// can straddle a batch boundary — the R3 shared-ks_s version was WRONG there).
// ---------------------------------------------------------------------------
template <int T>
__global__ __launch_bounds__(128) void epilogue(
    const float* __restrict__ qp, const float* __restrict__ v,
    const float* __restrict__ ksum, const float* __restrict__ kptv,
    const float* __restrict__ proj_w, const float* __restrict__ proj_b,
    const float* __restrict__ ln2_g, const float* __restrict__ ln2_b,
    const float* __restrict__ m1_w, const float* __restrict__ m1_b,
    const float* __restrict__ m2_w, const float* __restrict__ m2_b,
    float* __restrict__ out)
{
    const int sub = threadIdx.x >> 6;
    const int e = threadIdx.x & 63;
    const int tok0 = blockIdx.x * 32 + sub * 16;
    const int b = tok0 / T;    // per-sub batch (T % 16 == 0 within a sub-tile)

    __shared__ __align__(16) float qp_s[2][16 * 36];
    __shared__ __align__(16) float buf[2][64 * 20];
    __shared__ float ks_s[2][32];
    __shared__ float D_s[2][16];

    for (int idx = e; idx < 512; idx += 64)
        qp_s[sub][(idx >> 5) * 36 + (idx & 31)] = qp[(size_t)tok0 * 32 + idx];
    if (e < 32) ks_s[sub][e] = ksum[b * 32 + e];   // each wave loads its own b
    __syncthreads();
    if (e < 16) {
        float D = 1e-8f;
        for (int r = 0; r < 32; ++r) D += qp_s[sub][e * 36 + r] * ks_s[sub][r];
        D_s[sub][e] = D;
    }
    float4 kv4[8];
#pragma unroll
    for (int g = 0; g < 8; ++g)
        kv4[g] = *(const float4*)&kptv[(size_t)(b * 64 + e) * 32 + 4 * g];
    __syncthreads();

    float ya[16];
#pragma unroll
    for (int m = 0; m < 16; ++m) {
        const float4* q4 = (const float4*)&qp_s[sub][m * 36];
        float a = 0.f;
#pragma unroll
        for (int g = 0; g < 8; ++g) {
            const float4 qv = q4[g];
            a += qv.x*kv4[g].x + qv.y*kv4[g].y + qv.z*kv4[g].z + qv.w*kv4[g].w;
        }
        ya[m] = a / D_s[sub][m];
    }
#pragma unroll
    for (int g = 0; g < 4; ++g)
        *(float4*)&buf[sub][e * 20 + 4*g] = make_float4(ya[4*g], ya[4*g+1], ya[4*g+2], ya[4*g+3]);
    __syncthreads();

    float y[16];
    { float acc2[16];
      const float pb = proj_b[e];
#pragma unroll
      for (int m = 0; m < 16; ++m) acc2[m] = pb;
      for (int j = 0; j < 64; ++j) {
          const float w = proj_w[j * 64 + e];
          const float4* a4 = (const float4*)&buf[sub][j * 20];
#pragma unroll
          for (int g = 0; g < 4; ++g) {
              const float4 av = a4[g];
              acc2[4*g+0] += av.x * w; acc2[4*g+1] += av.y * w;
              acc2[4*g+2] += av.z * w; acc2[4*g+3] += av.w * w;
          }
      }
#pragma unroll
      for (int m = 0; m < 16; ++m)
          y[m] = v[(size_t)(tok0 + m) * 64 + e] + acc2[m];
    }
    __syncthreads();

    { const float g2 = ln2_g[e], bb = ln2_b[e];
      float z[16];
#pragma unroll
      for (int m = 0; m < 16; ++m) {
          const float s  = waveReduceSum(y[m]);
          const float s2 = waveReduceSum(y[m] * y[m]);
          const float mu = s * (1.f / 64.f);
          const float var = s2 * (1.f / 64.f) - mu * mu;
          z[m] = (y[m] - mu) * rsqrtf(var + 1e-5f) * g2 + bb;
      }
#pragma unroll
      for (int g = 0; g < 4; ++g)
          *(float4*)&buf[sub][e * 20 + 4*g] = make_float4(z[4*g], z[4*g+1], z[4*g+2], z[4*g+3]);
    }
    __syncthreads();

    float h[16];
    { const float b1 = m1_b[e];
#pragma unroll
      for (int m = 0; m < 16; ++m) h[m] = b1;
      for (int j = 0; j < 64; ++j) {
          const float w = m1_w[j * 64 + e];
          const float4* a4 = (const float4*)&buf[sub][j * 20];
#pragma unroll
          for (int g = 0; g < 4; ++g) {
              const float4 av = a4[g];
              h[4*g+0] += av.x * w; h[4*g+1] += av.y * w;
              h[4*g+2] += av.z * w; h[4*g+3] += av.w * w;
          }
      }
#pragma unroll
      for (int m = 0; m < 16; ++m)
          h[m] = 0.5f * h[m] * (1.f + erff(h[m] * 0.7071067811865476f));
    }
    __syncthreads();
#pragma unroll
    for (int g = 0; g < 4; ++g)
        *(float4*)&buf[sub][e * 20 + 4*g] = make_float4(h[4*g], h[4*g+1], h[4*g+2], h[4*g+3]);
    __syncthreads();

    { const float b2v = m2_b[e];
      float acc4[16];
#pragma unroll
      for (int m = 0; m < 16; ++m) acc4[m] = b2v;
      for (int j = 0; j < 64; ++j) {
          const float w = m2_w[j * 64 + e];
          const float4* a4 = (const float4*)&buf[sub][j * 20];
#pragma unroll
          for (int g = 0; g < 4; ++g) {
              const float4 av = a4[g];
              acc4[4*g+0] += av.x * w; acc4[4*g+1] += av.y * w;
              acc4[4*g+2] += av.z * w; acc4[4*g+3] += av.w * w;
          }
      }
#pragma unroll
      for (int m = 0; m < 16; ++m)
          out[(size_t)(tok0 + m) * 64 + e] = y[m] + acc4[m];
    }
}

// ---------------------------------------------------------------------------
// final: unfold(3,2,1) from o2 + dense 576->768. 16 tokens/block, 256 threads.
// ---------------------------------------------------------------------------
__global__ __launch_bounds__(256) void final_proj(
    const float* __restrict__ o2,    // (B*T2,64)
    const float* __restrict__ w,     // (576,768)
    const float* __restrict__ bias,  // (768)
    float* __restrict__ out)         // (B*T3,768)
{
    const int tok0 = blockIdx.x * 16;
    const int tid = threadIdx.x;
    __shared__ __align__(16) float ft[D2 * 20];

    { const int c = tid & 63, grp = tid >> 6;
      for (int u = grp; u < 16 * 9; u += 4) {
          const int m = u / 9, r = u % 9;
          const int tok = tok0 + m, b = tok / T3, t = tok % T3;
          const int py = t / 14, px = t % 14;
          const int ki = r / 3, kj = r % 3;
          const int iy = py * 2 - 1 + ki, ix = px * 2 - 1 + kj;
          float val = 0.f;
          if (iy >= 0 && iy < 28 && ix >= 0 && ix < 28)
              val = o2[(size_t)(b * T2 + iy * 28 + ix) * 64 + c];
          ft[(c * 9 + r) * 20 + m] = val;
      }
    }
    __syncthreads();

    float acc[3][16];
    { const float b0 = bias[tid], b1 = bias[tid + 256], b2 = bias[tid + 512];
#pragma unroll
      for (int m = 0; m < 16; ++m) { acc[0][m] = b0; acc[1][m] = b1; acc[2][m] = b2; }
    }
    for (int d = 0; d < D2; ++d) {
        const float w0 = w[d * 768 + tid];
        const float w1 = w[d * 768 + tid + 256];
        const float w2 = w[d * 768 + tid + 512];
        const float4* f4 = (const float4*)&ft[d * 20];
#pragma unroll
        for (int g = 0; g < 4; ++g) {
            const float4 f = f4[g];
            acc[0][4*g+0] += f.x * w0; acc[0][4*g+1] += f.y * w0;
            acc[0][4*g+2] += f.z * w0; acc[0][4*g+3] += f.w * w0;
            acc[1][4*g+0] += f.x * w1; acc[1][4*g+1] += f.y * w1;
            acc[1][4*g+2] += f.z * w1; acc[1][4*g+3] += f.w * w1;
            acc[2][4*g+0] += f.x * w2; acc[2][4*g+1] += f.y * w2;
            acc[2][4*g+2] += f.z * w2; acc[2][4*g+3] += f.w * w2;
        }
    }
#pragma unroll
    for (int m = 0; m < 16; ++m) {
        const size_t ob = (size_t)(tok0 + m) * 768 + tid;
        out[ob]       = acc[0][m];
        out[ob + 256] = acc[1][m];
        out[ob + 512] = acc[2][m];
    }
}

// ---------------------------------------------------------------------------
extern "C" void kernel_launch(void* const* d_in, const int* in_sizes, int n_in,
                              void* d_out, int out_size, void* d_ws, size_t ws_size,
                              hipStream_t stream) {
    const float* x         = (const float*)d_in[0];
    const float* p1_kqv_w  = (const float*)d_in[1];
    const float* p1_kqv_b  = (const float*)d_in[2];
    const float* p1_proj_w = (const float*)d_in[3];
    const float* p1_proj_b = (const float*)d_in[4];
    const float* p1_ln1_g  = (const float*)d_in[5];
    const float* p1_ln1_b  = (const float*)d_in[6];
    const float* p1_ln2_g  = (const float*)d_in[7];
    const float* p1_ln2_b  = (const float*)d_in[8];
    const float* p1_m1_w   = (const float*)d_in[9];
    const float* p1_m1_b   = (const float*)d_in[10];
    const float* p1_m2_w   = (const float*)d_in[11];
    const float* p1_m2_b   = (const float*)d_in[12];
    const float* p1_rf     = (const float*)d_in[13];
    const float* p2_kqv_w  = (const float*)d_in[14];
    const float* p2_kqv_b  = (const float*)d_in[15];
    const float* p2_proj_w = (const float*)d_in[16];
    const float* p2_proj_b = (const float*)d_in[17];
    const float* p2_ln1_g  = (const float*)d_in[18];
    const float* p2_ln1_b  = (const float*)d_in[19];
    const float* p2_ln2_g  = (const float*)d_in[20];
    const float* p2_ln2_b  = (const float*)d_in[21];
    const float* p2_m1_w   = (const float*)d_in[22];
    const float* p2_m1_b   = (const float*)d_in[23];
    const float* p2_m2_w   = (const float*)d_in[24];
    const float* p2_m2_b   = (const float*)d_in[25];
    const float* p2_rf     = (const float*)d_in[26];
    const float* proj_w    = (const float*)d_in[27];
    const float* proj_b    = (const float*)d_in[28];

    float* ws = (float*)d_ws;
    size_t off = 0;
    float* ksum1 = ws + off; off += (size_t)NB * 32;
    float* kptv1 = ws + off; off += (size_t)NB * 64 * 32;
    float* ksum2 = ws + off; off += (size_t)NB * 32;
    float* kptv2 = ws + off; off += (size_t)NB * 64 * 32;
    const size_t zero_bytes = off * sizeof(float);
    float* kp1 = ws + off; off += (size_t)NB * T1 * 32;
    float* qp1 = ws + off; off += (size_t)NB * T1 * 32;
    float* v1  = ws + off; off += (size_t)NB * T1 * 64;
    float* o1  = ws + off; off += (size_t)NB * T1 * 64;
    size_t off2 = 0;
    float* kp2 = kp1 + off2; off2 += (size_t)NB * T2 * 32;
    float* qp2 = kp1 + off2; off2 += (size_t)NB * T2 * 32;
    float* v2  = kp1 + off2; off2 += (size_t)NB * T2 * 64;
    float* o2  = kp1 + off2; off2 += (size_t)NB * T2 * 64;

    hipMemsetAsync(ws, 0, zero_bytes, stream);

    front1<<<NB * T1 / 32, 256, 0, stream>>>(x, p1_kqv_w, p1_kqv_b, p1_ln1_g,
                                             p1_ln1_b, p1_rf, kp1, qp1, v1);
    reduce_kv<T1, 14><<<NB * 14, 256, 0, stream>>>(kp1, v1, ksum1, kptv1);
    epilogue<T1><<<NB * T1 / 32, 128, 0, stream>>>(qp1, v1, ksum1, kptv1,
                                                   p1_proj_w, p1_proj_b, p1_ln2_g, p1_ln2_b,
                                                   p1_m1_w, p1_m1_b, p1_m2_w, p1_m2_b, o1);
    front2<<<NB * T2 / 16, 128, 0, stream>>>(o1, p2_kqv_w, p2_kqv_b, p2_ln1_g,
                                             p2_ln1_b, p2_rf, kp2, qp2, v2);
    reduce_kv<T2, 7><<<NB * 7, 256, 0, stream>>>(kp2, v2, ksum2, kptv2);
    epilogue<T2><<<NB * T2 / 32, 128, 0, stream>>>(qp2, v2, ksum2, kptv2,
                                                   p2_proj_w, p2_proj_b, p2_ln2_g, p2_ln2_b,
                                                   p2_m1_w, p2_m1_b, p2_m2_w, p2_m2_b, o2);
    final_proj<<<NB * T3 / 16, 256, 0, stream>>>(o2, proj_w, proj_b, (float*)d_out);
}

// Round 8
// 1437.251 us; speedup vs baseline: 1.1128x; 1.1128x over previous
//
#include <hip/hip_runtime.h>
#include <hip/hip_bf16.h>

#define NB 64
#define T1 3136
#define T2 784
#define T3 196
#define D1 147
#define D2 576

__device__ __forceinline__ float waveReduceSum(float v) {
#pragma unroll
    for (int off = 32; off > 0; off >>= 1) v += __shfl_down(v, off, 64);
    return __shfl(v, 0, 64);
}

// ---------------------------------------------------------------------------
// front1: 32 tokens/block, 256 threads. unfold(7,4,2) + LN + kqv + prm_exp.
// Thread owns 3 cols x 8 tokens. Weight register-prefetch, group of 3 d's.
// ---------------------------------------------------------------------------
__global__ __launch_bounds__(256) void front1(
    const float* __restrict__ x,
    const float* __restrict__ kqv_w,   // (147,192)
    const float* __restrict__ kqv_b,   // (192)
    const float* __restrict__ ln_g, const float* __restrict__ ln_b,  // (147)
    const float* __restrict__ rf,      // (32,64)
    float* __restrict__ kp, float* __restrict__ qp,   // (B*T1,32)
    float* __restrict__ v_out)                        // (B*T1,64)
{
    const int tok0 = blockIdx.x * 32;
    const int b = tok0 / T1;
    const int tbase = tok0 % T1;   // T1 % 32 == 0
    const int tid = threadIdx.x;
    const int c = tid & 63, tg = tid >> 6;
    const int lane = tid & 63;

    __shared__ __align__(16) float smem[D1 * 36];   // ft[d][m] pad36; kq aliases
    __shared__ float ps_sum[256], ps_sq[256];
    __shared__ float mu_s[32], rs_s[32];
    __shared__ float xd_s[64];

    float* ft  = smem;
    float* kqs = smem;   // [2][32][64] after matvec

    float4 rfr[16];
    { const float* rp = rf + (size_t)(tid & 31) * 64;
#pragma unroll
      for (int g = 0; g < 16; ++g) rfr[g] = *(const float4*)(rp + 4 * g); }

    for (int idx = tid; idx < D1 * 32; idx += 256) {
        const int m = idx & 31, d = idx >> 5;
        const int t = tbase + m;
        const int py = t / 56, px = t % 56;
        const int cc = d / 49, r = d % 49, ki = r / 7, kj = r % 7;
        const int iy = py * 4 - 2 + ki, ix = px * 4 - 2 + kj;
        float val = 0.f;
        if (iy >= 0 && iy < 224 && ix >= 0 && ix < 224)
            val = x[((b * 3 + cc) * 224 + iy) * 224 + ix];
        ft[d * 36 + m] = val;
    }
    __syncthreads();

    { const int m = tid & 31, j = tid >> 5;
      float s = 0.f, s2 = 0.f;
      for (int d = j; d < D1; d += 8) { const float u = ft[d*36+m]; s += u; s2 += u*u; }
      ps_sum[tid] = s; ps_sq[tid] = s2; }
    __syncthreads();
    if (tid < 32) {
        float s = 0.f, s2 = 0.f;
        for (int j = 0; j < 8; ++j) { s += ps_sum[j*32+tid]; s2 += ps_sq[j*32+tid]; }
        const float mu = s * (1.f / D1);
        const float var = s2 * (1.f / D1) - mu * mu;
        mu_s[tid] = mu; rs_s[tid] = rsqrtf(var + 1e-5f);
    }
    __syncthreads();
    for (int idx = tid; idx < D1 * 32; idx += 256) {
        const int m = idx & 31, d = idx >> 5;
        ft[d*36+m] = (ft[d*36+m] - mu_s[m]) * rs_s[m] * ln_g[d] + ln_b[d];
    }
    __syncthreads();

    // matvec: 3 cols x 8 tokens per thread; weight prefetch (group of 3 d)
    float acc[3][8];
    { const float b0 = kqv_b[c], b1 = kqv_b[64 + c], b2 = kqv_b[128 + c];
#pragma unroll
      for (int m = 0; m < 8; ++m) { acc[0][m] = b0; acc[1][m] = b1; acc[2][m] = b2; } }

    float w0[3], w1[3], w2[3], n0[3], n1[3], n2[3];
    { const float* wp = kqv_w + c;
#pragma unroll
      for (int i = 0; i < 3; ++i) { w0[i] = wp[i*192]; w1[i] = wp[i*192+64]; w2[i] = wp[i*192+128]; } }
    for (int dg = 0; dg < 49; ++dg) {
        if (dg < 48) {
            const float* wp = kqv_w + (dg * 3 + 3) * 192 + c;
#pragma unroll
            for (int i = 0; i < 3; ++i) { n0[i] = wp[i*192]; n1[i] = wp[i*192+64]; n2[i] = wp[i*192+128]; }
        }
#pragma unroll
        for (int i = 0; i < 3; ++i) {
            const int d = dg * 3 + i;
            const float4 f0 = *(const float4*)&ft[d * 36 + 8 * tg];
            const float4 f1 = *(const float4*)&ft[d * 36 + 8 * tg + 4];
            acc[0][0] += f0.x*w0[i]; acc[0][1] += f0.y*w0[i]; acc[0][2] += f0.z*w0[i]; acc[0][3] += f0.w*w0[i];
            acc[0][4] += f1.x*w0[i]; acc[0][5] += f1.y*w0[i]; acc[0][6] += f1.z*w0[i]; acc[0][7] += f1.w*w0[i];
            acc[1][0] += f0.x*w1[i]; acc[1][1] += f0.y*w1[i]; acc[1][2] += f0.z*w1[i]; acc[1][3] += f0.w*w1[i];
            acc[1][4] += f1.x*w1[i]; acc[1][5] += f1.y*w1[i]; acc[1][6] += f1.z*w1[i]; acc[1][7] += f1.w*w1[i];
            acc[2][0] += f0.x*w2[i]; acc[2][1] += f0.y*w2[i]; acc[2][2] += f0.z*w2[i]; acc[2][3] += f0.w*w2[i];
            acc[2][4] += f1.x*w2[i]; acc[2][5] += f1.y*w2[i]; acc[2][6] += f1.z*w2[i]; acc[2][7] += f1.w*w2[i];
        }
#pragma unroll
        for (int i = 0; i < 3; ++i) { w0[i] = n0[i]; w1[i] = n1[i]; w2[i] = n2[i]; }
    }
    __syncthreads();   // all ft reads done before kqs aliases it

#pragma unroll
    for (int m = 0; m < 8; ++m)
        v_out[(size_t)(tok0 + 8 * tg + m) * 64 + c] = acc[2][m];
#pragma unroll
    for (int m = 0; m < 8; ++m) {
        kqs[(0 * 32 + 8 * tg + m) * 64 + c] = acc[0][m];
        kqs[(1 * 32 + 8 * tg + m) * 64 + c] = acc[1][m];
    }
#pragma unroll
    for (int m = 0; m < 8; ++m) {
        const float sk = waveReduceSum(acc[0][m] * acc[0][m]);
        const float sq = waveReduceSum(acc[1][m] * acc[1][m]);
        if (lane == 0) { xd_s[8 * tg + m] = 0.5f * sk; xd_s[32 + 8 * tg + m] = 0.5f * sq; }
    }
    __syncthreads();

    for (int slot = tid; slot < 2048; slot += 256) {
        const int half = slot >> 10, rem = slot & 1023;
        const int m = rem >> 5, mrf = slot & 31;
        const float4* k4 = (const float4*)&kqs[(half * 32 + m) * 64];
        float a = 0.f;
#pragma unroll
        for (int g = 0; g < 16; ++g) {
            const float4 kv = k4[g];
            a += rfr[g].x*kv.x + rfr[g].y*kv.y + rfr[g].z*kv.z + rfr[g].w*kv.w;
        }
        const float p = expf(a - xd_s[half * 32 + m]) * 0.1767766952966369f;
        (half ? qp : kp)[(size_t)(tok0 + m) * 32 + mrf] = p;
    }
}

// ---------------------------------------------------------------------------
// front2: 16 tokens/block, 128 threads. unfold(3,2,1) + LN + kqv + prm_exp.
// Weight register-prefetch, group of 4 d's (576 = 4*144).
// ---------------------------------------------------------------------------
__global__ __launch_bounds__(128) void front2(
    const float* __restrict__ src,     // o1 (B*T1,64)
    const float* __restrict__ kqv_w,   // (576,192)
    const float* __restrict__ kqv_b,
    const float* __restrict__ ln_g, const float* __restrict__ ln_b,  // (576)
    const float* __restrict__ rf,
    float* __restrict__ kp, float* __restrict__ qp,   // (B*T2,32)
    float* __restrict__ v_out)                        // (B*T2,64)
{
    const int tok0 = blockIdx.x * 16;
    const int b = tok0 / T2;
    const int tbase = tok0 % T2;   // T2 % 16 == 0
    const int tid = threadIdx.x;
    const int c = tid & 63, tg = tid >> 6;
    const int lane = tid & 63;

    __shared__ __align__(16) float smem[D2 * 20];   // ft; kq aliases
    __shared__ float ps_sum[128], ps_sq[128];
    __shared__ float mu_s[16], rs_s[16];
    __shared__ float xd_s[32];

    float* ft  = smem;
    float* kqs = smem;    // [2][16][64]

    float4 rfr[16];
    { const float* rp = rf + (size_t)(tid & 31) * 64;
#pragma unroll
      for (int g = 0; g < 16; ++g) rfr[g] = *(const float4*)(rp + 4 * g); }

    for (int u = tg; u < 16 * 9; u += 2) {
        const int m = u / 9, r = u % 9;
        const int t = tbase + m;
        const int py = t / 28, px = t % 28;
        const int ki = r / 3, kj = r % 3;
        const int iy = py * 2 - 1 + ki, ix = px * 2 - 1 + kj;
        float val = 0.f;
        if (iy >= 0 && iy < 56 && ix >= 0 && ix < 56)
            val = src[(size_t)(b * T1 + iy * 56 + ix) * 64 + c];
        ft[(c * 9 + r) * 20 + m] = val;
    }
    __syncthreads();

    { const int m = tid & 15, j = tid >> 4;
      float s = 0.f, s2 = 0.f;
      for (int d = j; d < D2; d += 8) { const float u = ft[d*20+m]; s += u; s2 += u*u; }
      ps_sum[tid] = s; ps_sq[tid] = s2; }
    __syncthreads();
    if (tid < 16) {
        float s = 0.f, s2 = 0.f;
        for (int j = 0; j < 8; ++j) { s += ps_sum[j*16+tid]; s2 += ps_sq[j*16+tid]; }
        const float mu = s * (1.f / D2);
        const float var = s2 * (1.f / D2) - mu * mu;
        mu_s[tid] = mu; rs_s[tid] = rsqrtf(var + 1e-5f);
    }
    __syncthreads();
    for (int idx = tid; idx < D2 * 16; idx += 128) {
        const int m = idx & 15, d = idx >> 4;
        ft[d*20+m] = (ft[d*20+m] - mu_s[m]) * rs_s[m] * ln_g[d] + ln_b[d];
    }
    __syncthreads();

    float acc[3][8];
    { const float b0 = kqv_b[c], b1 = kqv_b[64 + c], b2 = kqv_b[128 + c];
#pragma unroll
      for (int m = 0; m < 8; ++m) { acc[0][m] = b0; acc[1][m] = b1; acc[2][m] = b2; } }

    float w0[4], w1[4], w2[4], n0[4], n1[4], n2[4];
    { const float* wp = kqv_w + c;
#pragma unroll
      for (int i = 0; i < 4; ++i) { w0[i] = wp[i*192]; w1[i] = wp[i*192+64]; w2[i] = wp[i*192+128]; } }
    for (int dg = 0; dg < 144; ++dg) {
        if (dg < 143) {
            const float* wp = kqv_w + (dg * 4 + 4) * 192 + c;
#pragma unroll
            for (int i = 0; i < 4; ++i) { n0[i] = wp[i*192]; n1[i] = wp[i*192+64]; n2[i] = wp[i*192+128]; }
        }
#pragma unroll
        for (int i = 0; i < 4; ++i) {
            const int d = dg * 4 + i;
            const float4 f0 = *(const float4*)&ft[d * 20 + 8 * tg];
            const float4 f1 = *(const float4*)&ft[d * 20 + 8 * tg + 4];
            acc[0][0] += f0.x*w0[i]; acc[0][1] += f0.y*w0[i]; acc[0][2] += f0.z*w0[i]; acc[0][3] += f0.w*w0[i];
            acc[0][4] += f1.x*w0[i]; acc[0][5] += f1.y*w0[i]; acc[0][6] += f1.z*w0[i]; acc[0][7] += f1.w*w0[i];
            acc[1][0] += f0.x*w1[i]; acc[1][1] += f0.y*w1[i]; acc[1][2] += f0.z*w1[i]; acc[1][3] += f0.w*w1[i];
            acc[1][4] += f1.x*w1[i]; acc[1][5] += f1.y*w1[i]; acc[1][6] += f1.z*w1[i]; acc[1][7] += f1.w*w1[i];
            acc[2][0] += f0.x*w2[i]; acc[2][1] += f0.y*w2[i]; acc[2][2] += f0.z*w2[i]; acc[2][3] += f0.w*w2[i];
            acc[2][4] += f1.x*w2[i]; acc[2][5] += f1.y*w2[i]; acc[2][6] += f1.z*w2[i]; acc[2][7] += f1.w*w2[i];
        }
#pragma unroll
        for (int i = 0; i < 4; ++i) { w0[i] = n0[i]; w1[i] = n1[i]; w2[i] = n2[i]; }
    }
    __syncthreads();

#pragma unroll
    for (int m = 0; m < 8; ++m)
        v_out[(size_t)(tok0 + 8 * tg + m) * 64 + c] = acc[2][m];
#pragma unroll
    for (int m = 0; m < 8; ++m) {
        kqs[(0 * 16 + 8 * tg + m) * 64 + c] = acc[0][m];
        kqs[(1 * 16 + 8 * tg + m) * 64 + c] = acc[1][m];
    }
#pragma unroll
    for (int m = 0; m < 8; ++m) {
        const float sk = waveReduceSum(acc[0][m] * acc[0][m]);
        const float sq = waveReduceSum(acc[1][m] * acc[1][m]);
        if (lane == 0) { xd_s[8 * tg + m] = 0.5f * sk; xd_s[16 + 8 * tg + m] = 0.5f * sq; }
    }
    __syncthreads();

    for (int slot = tid; slot < 1024; slot += 128) {
        const int half = slot >> 9, rem = slot & 511;
        const int m = rem >> 5, mrf = slot & 31;
        const float4* k4 = (const float4*)&kqs[(half * 16 + m) * 64];
        float a = 0.f;
#pragma unroll
        for (int g = 0; g < 16; ++g) {
            const float4 kv = k4[g];
            a += rfr[g].x*kv.x + rfr[g].y*kv.y + rfr[g].z*kv.z + rfr[g].w*kv.w;
        }
        const float p = expf(a - xd_s[half * 16 + m]) * 0.1767766952966369f;
        (half ? qp : kp)[(size_t)(tok0 + m) * 32 + mrf] = p;
    }
}

// ---------------------------------------------------------------------------
// reduce_kv, split S-ways over T with atomics (ksum/kptv pre-zeroed)
// ---------------------------------------------------------------------------
template <int T, int S>
__global__ __launch_bounds__(256) void reduce_kv(
    const float* __restrict__ kp, const float* __restrict__ v,
    float* __restrict__ ksum, float* __restrict__ kptv)
{
    const int b = blockIdx.x / S, s = blockIdx.x % S;
    const int chunk = T / S;
    const int tid = threadIdx.x;
    __shared__ float kp_s[8][32];
    __shared__ float v_s[8][64];
    float acc[8] = {0.f, 0.f, 0.f, 0.f, 0.f, 0.f, 0.f, 0.f};
    float ks = 0.f;
    const int n = tid >> 2;
    const int mb = (tid & 3) * 8;
    const float* kpb = kp + (size_t)b * T * 32;
    const float* vb  = v  + (size_t)b * T * 64;

    for (int t0 = s * chunk; t0 < (s + 1) * chunk; t0 += 8) {
        kp_s[tid >> 5][tid & 31] = kpb[(t0 + (tid >> 5)) * 32 + (tid & 31)];
        {
            const int i0 = tid * 2, i1 = tid * 2 + 1;
            v_s[i0 >> 6][i0 & 63] = vb[(t0 + (i0 >> 6)) * 64 + (i0 & 63)];
            v_s[i1 >> 6][i1 & 63] = vb[(t0 + (i1 >> 6)) * 64 + (i1 & 63)];
        }
        __syncthreads();
#pragma unroll
        for (int tt = 0; tt < 8; ++tt) {
            const float vv = v_s[tt][n];
#pragma unroll
            for (int i = 0; i < 8; ++i) acc[i] += vv * kp_s[tt][mb + i];
        }
        if (tid < 32) {
#pragma unroll
            for (int tt = 0; tt < 8; ++tt) ks += kp_s[tt][tid];
        }
        __syncthreads();
    }
#pragma unroll
    for (int i = 0; i < 8; ++i) atomicAdd(&kptv[(b * 64 + n) * 32 + mb + i], acc[i]);
    if (tid < 32) atomicAdd(&ksum[b * 32 + tid], ks);
}

// ---------------------------------------------------------------------------
// epilogue: 128 threads = two independent 16-token tiles; per-sub ksum.
// ---------------------------------------------------------------------------
template <int T>
__global__ __launch_bounds__(128) void epilogue(
    const float* __restrict__ qp, const float* __restrict__ v,
    const float* __restrict__ ksum, const float* __restrict__ kptv,
    const float* __restrict__ proj_w, const float* __restrict__ proj_b,
    const float* __restrict__ ln2_g, const float* __restrict__ ln2_b,
    const float* __restrict__ m1_w, const float* __restrict__ m1_b,
    const float* __restrict__ m2_w, const float* __restrict__ m2_b,
    float* __restrict__ out)
{
    const int sub = threadIdx.x >> 6;
    const int e = threadIdx.x & 63;
    const int tok0 = blockIdx.x * 32 + sub * 16;
    const int b = tok0 / T;

    __shared__ __align__(16) float qp_s[2][16 * 36];
    __shared__ __align__(16) float buf[2][64 * 20];
    __shared__ float ks_s[2][32];
    __shared__ float D_s[2][16];

    for (int idx = e; idx < 512; idx += 64)
        qp_s[sub][(idx >> 5) * 36 + (idx & 31)] = qp[(size_t)tok0 * 32 + idx];
    if (e < 32) ks_s[sub][e] = ksum[b * 32 + e];
    __syncthreads();
    if (e < 16) {
        float D = 1e-8f;
        for (int r = 0; r < 32; ++r) D += qp_s[sub][e * 36 + r] * ks_s[sub][r];
        D_s[sub][e] = D;
    }
    float4 kv4[8];
#pragma unroll
    for (int g = 0; g < 8; ++g)
        kv4[g] = *(const float4*)&kptv[(size_t)(b * 64 + e) * 32 + 4 * g];
    __syncthreads();

    float ya[16];
#pragma unroll
    for (int m = 0; m < 16; ++m) {
        const float4* q4 = (const float4*)&qp_s[sub][m * 36];
        float a = 0.f;
#pragma unroll
        for (int g = 0; g < 8; ++g) {
            const float4 qv = q4[g];
            a += qv.x*kv4[g].x + qv.y*kv4[g].y + qv.z*kv4[g].z + qv.w*kv4[g].w;
        }
        ya[m] = a / D_s[sub][m];
    }
#pragma unroll
    for (int g = 0; g < 4; ++g)
        *(float4*)&buf[sub][e * 20 + 4*g] = make_float4(ya[4*g], ya[4*g+1], ya[4*g+2], ya[4*g+3]);
    __syncthreads();

    float y[16];
    { float acc2[16];
      const float pb = proj_b[e];
#pragma unroll
      for (int m = 0; m < 16; ++m) acc2[m] = pb;
      for (int j = 0; j < 64; ++j) {
          const float w = proj_w[j * 64 + e];
          const float4* a4 = (const float4*)&buf[sub][j * 20];
#pragma unroll
          for (int g = 0; g < 4; ++g) {
              const float4 av = a4[g];
              acc2[4*g+0] += av.x * w; acc2[4*g+1] += av.y * w;
              acc2[4*g+2] += av.z * w; acc2[4*g+3] += av.w * w;
          }
      }
#pragma unroll
      for (int m = 0; m < 16; ++m)
          y[m] = v[(size_t)(tok0 + m) * 64 + e] + acc2[m];
    }
    __syncthreads();

    { const float g2 = ln2_g[e], bb = ln2_b[e];
      float z[16];
#pragma unroll
      for (int m = 0; m < 16; ++m) {
          const float s  = waveReduceSum(y[m]);
          const float s2 = waveReduceSum(y[m] * y[m]);
          const float mu = s * (1.f / 64.f);
          const float var = s2 * (1.f / 64.f) - mu * mu;
          z[m] = (y[m] - mu) * rsqrtf(var + 1e-5f) * g2 + bb;
      }
#pragma unroll
      for (int g = 0; g < 4; ++g)
          *(float4*)&buf[sub][e * 20 + 4*g] = make_float4(z[4*g], z[4*g+1], z[4*g+2], z[4*g+3]);
    }
    __syncthreads();

    float h[16];
    { const float b1 = m1_b[e];
#pragma unroll
      for (int m = 0; m < 16; ++m) h[m] = b1;
      for (int j = 0; j < 64; ++j) {
          const float w = m1_w[j * 64 + e];
          const float4* a4 = (const float4*)&buf[sub][j * 20];
#pragma unroll
          for (int g = 0; g < 4; ++g) {
              const float4 av = a4[g];
              h[4*g+0] += av.x * w; h[4*g+1] += av.y * w;
              h[4*g+2] += av.z * w; h[4*g+3] += av.w * w;
          }
      }
#pragma unroll
      for (int m = 0; m < 16; ++m)
          h[m] = 0.5f * h[m] * (1.f + erff(h[m] * 0.7071067811865476f));
    }
    __syncthreads();
#pragma unroll
    for (int g = 0; g < 4; ++g)
        *(float4*)&buf[sub][e * 20 + 4*g] = make_float4(h[4*g], h[4*g+1], h[4*g+2], h[4*g+3]);
    __syncthreads();

    { const float b2v = m2_b[e];
      float acc4[16];
#pragma unroll
      for (int m = 0; m < 16; ++m) acc4[m] = b2v;
      for (int j = 0; j < 64; ++j) {
          const float w = m2_w[j * 64 + e];
          const float4* a4 = (const float4*)&buf[sub][j * 20];
#pragma unroll
          for (int g = 0; g < 4; ++g) {
              const float4 av = a4[g];
              acc4[4*g+0] += av.x * w; acc4[4*g+1] += av.y * w;
              acc4[4*g+2] += av.z * w; acc4[4*g+3] += av.w * w;
          }
      }
#pragma unroll
      for (int m = 0; m < 16; ++m)
          out[(size_t)(tok0 + m) * 64 + e] = y[m] + acc4[m];
    }
}

// ---------------------------------------------------------------------------
// final: unfold(3,2,1) from o2 + dense 576->768. 16 tokens/block, 256 threads.
// Weight register-prefetch, group of 4 d's.
// ---------------------------------------------------------------------------
__global__ __launch_bounds__(256) void final_proj(
    const float* __restrict__ o2,    // (B*T2,64)
    const float* __restrict__ w,     // (576,768)
    const float* __restrict__ bias,  // (768)
    float* __restrict__ out)         // (B*T3,768)
{
    const int tok0 = blockIdx.x * 16;
    const int tid = threadIdx.x;
    __shared__ __align__(16) float ft[D2 * 20];

    { const int c = tid & 63, grp = tid >> 6;
      for (int u = grp; u < 16 * 9; u += 4) {
          const int m = u / 9, r = u % 9;
          const int tok = tok0 + m, b = tok / T3, t = tok % T3;
          const int py = t / 14, px = t % 14;
          const int ki = r / 3, kj = r % 3;
          const int iy = py * 2 - 1 + ki, ix = px * 2 - 1 + kj;
          float val = 0.f;
          if (iy >= 0 && iy < 28 && ix >= 0 && ix < 28)
              val = o2[(size_t)(b * T2 + iy * 28 + ix) * 64 + c];
          ft[(c * 9 + r) * 20 + m] = val;
      }
    }
    __syncthreads();

    float acc[3][16];
    { const float b0 = bias[tid], b1 = bias[tid + 256], b2 = bias[tid + 512];
#pragma unroll
      for (int m = 0; m < 16; ++m) { acc[0][m] = b0; acc[1][m] = b1; acc[2][m] = b2; }
    }

    float w0[4], w1[4], w2[4], n0[4], n1[4], n2[4];
    { const float* wp = w + tid;
#pragma unroll
      for (int i = 0; i < 4; ++i) { w0[i] = wp[i*768]; w1[i] = wp[i*768+256]; w2[i] = wp[i*768+512]; } }
    for (int dg = 0; dg < 144; ++dg) {
        if (dg < 143) {
            const float* wp = w + (dg * 4 + 4) * 768 + tid;
#pragma unroll
            for (int i = 0; i < 4; ++i) { n0[i] = wp[i*768]; n1[i] = wp[i*768+256]; n2[i] = wp[i*768+512]; }
        }
#pragma unroll
        for (int i = 0; i < 4; ++i) {
            const int d = dg * 4 + i;
            const float4* f4 = (const float4*)&ft[d * 20];
#pragma unroll
            for (int g = 0; g < 4; ++g) {
                const float4 f = f4[g];
                acc[0][4*g+0] += f.x * w0[i]; acc[0][4*g+1] += f.y * w0[i];
                acc[0][4*g+2] += f.z * w0[i]; acc[0][4*g+3] += f.w * w0[i];
                acc[1][4*g+0] += f.x * w1[i]; acc[1][4*g+1] += f.y * w1[i];
                acc[1][4*g+2] += f.z * w1[i]; acc[1][4*g+3] += f.w * w1[i];
                acc[2][4*g+0] += f.x * w2[i]; acc[2][4*g+1] += f.y * w2[i];
                acc[2][4*g+2] += f.z * w2[i]; acc[2][4*g+3] += f.w * w2[i];
            }
        }
#pragma unroll
        for (int i = 0; i < 4; ++i) { w0[i] = n0[i]; w1[i] = n1[i]; w2[i] = n2[i]; }
    }
#pragma unroll
    for (int m = 0; m < 16; ++m) {
        const size_t ob = (size_t)(tok0 + m) * 768 + tid;
        out[ob]       = acc[0][m];
        out[ob + 256] = acc[1][m];
        out[ob + 512] = acc[2][m];
    }
}

// ---------------------------------------------------------------------------
extern "C" void kernel_launch(void* const* d_in, const int* in_sizes, int n_in,
                              void* d_out, int out_size, void* d_ws, size_t ws_size,
                              hipStream_t stream) {
    const float* x         = (const float*)d_in[0];
    const float* p1_kqv_w  = (const float*)d_in[1];
    const float* p1_kqv_b  = (const float*)d_in[2];
    const float* p1_proj_w = (const float*)d_in[3];
    const float* p1_proj_b = (const float*)d_in[4];
    const float* p1_ln1_g  = (const float*)d_in[5];
    const float* p1_ln1_b  = (const float*)d_in[6];
    const float* p1_ln2_g  = (const float*)d_in[7];
    const float* p1_ln2_b  = (const float*)d_in[8];
    const float* p1_m1_w   = (const float*)d_in[9];
    const float* p1_m1_b   = (const float*)d_in[10];
    const float* p1_m2_w   = (const float*)d_in[11];
    const float* p1_m2_b   = (const float*)d_in[12];
    const float* p1_rf     = (const float*)d_in[13];
    const float* p2_kqv_w  = (const float*)d_in[14];
    const float* p2_kqv_b  = (const float*)d_in[15];
    const float* p2_proj_w = (const float*)d_in[16];
    const float* p2_proj_b = (const float*)d_in[17];
    const float* p2_ln1_g  = (const float*)d_in[18];
    const float* p2_ln1_b  = (const float*)d_in[19];
    const float* p2_ln2_g  = (const float*)d_in[20];
    const float* p2_ln2_b  = (const float*)d_in[21];
    const float* p2_m1_w   = (const float*)d_in[22];
    const float* p2_m1_b   = (const float*)d_in[23];
    const float* p2_m2_w   = (const float*)d_in[24];
    const float* p2_m2_b   = (const float*)d_in[25];
    const float* p2_rf     = (const float*)d_in[26];
    const float* proj_w    = (const float*)d_in[27];
    const float* proj_b    = (const float*)d_in[28];

    float* ws = (float*)d_ws;
    size_t off = 0;
    float* ksum1 = ws + off; off += (size_t)NB * 32;
    float* kptv1 = ws + off; off += (size_t)NB * 64 * 32;
    float* ksum2 = ws + off; off += (size_t)NB * 32;
    float* kptv2 = ws + off; off += (size_t)NB * 64 * 32;
    const size_t zero_bytes = off * sizeof(float);
    float* kp1 = ws + off; off += (size_t)NB * T1 * 32;
    float* qp1 = ws + off; off += (size_t)NB * T1 * 32;
    float* v1  = ws + off; off += (size_t)NB * T1 * 64;
    float* o1  = ws + off; off += (size_t)NB * T1 * 64;
    size_t off2 = 0;
    float* kp2 = kp1 + off2; off2 += (size_t)NB * T2 * 32;
    float* qp2 = kp1 + off2; off2 += (size_t)NB * T2 * 32;
    float* v2  = kp1 + off2; off2 += (size_t)NB * T2 * 64;
    float* o2  = kp1 + off2; off2 += (size_t)NB * T2 * 64;

    hipMemsetAsync(ws, 0, zero_bytes, stream);

    front1<<<NB * T1 / 32, 256, 0, stream>>>(x, p1_kqv_w, p1_kqv_b, p1_ln1_g,
                                             p1_ln1_b, p1_rf, kp1, qp1, v1);
    reduce_kv<T1, 14><<<NB * 14, 256, 0, stream>>>(kp1, v1, ksum1, kptv1);
    epilogue<T1><<<NB * T1 / 32, 128, 0, stream>>>(qp1, v1, ksum1, kptv1,
                                                   p1_proj_w, p1_proj_b, p1_ln2_g, p1_ln2_b,
                                                   p1_m1_w, p1_m1_b, p1_m2_w, p1_m2_b, o1);
    front2<<<NB * T2 / 16, 128, 0, stream>>>(o1, p2_kqv_w, p2_kqv_b, p2_ln1_g,
                                             p2_ln1_b, p2_rf, kp2, qp2, v2);
    reduce_kv<T2, 7><<<NB * 7, 256, 0, stream>>>(kp2, v2, ksum2, kptv2);
    epilogue<T2><<<NB * T2 / 32, 128, 0, stream>>>(qp2, v2, ksum2, kptv2,
                                                   p2_proj_w, p2_proj_b, p2_ln2_g, p2_ln2_b,
                                                   p2_m1_w, p2_m1_b, p2_m2_w, p2_m2_b, o2);
    final_proj<<<NB * T3 / 16, 256, 0, stream>>>(o2, proj_w, proj_b, (float*)d_out);
}

// Round 9
// 1289.661 us; speedup vs baseline: 1.2401x; 1.1144x over previous
//
#include <hip/hip_runtime.h>
#include <hip/hip_bf16.h>

#define NB 64
#define T1 3136
#define T2 784
#define T3 196
#define D1 147
#define D2 576

__device__ __forceinline__ float waveReduceSum(float v) {
#pragma unroll
    for (int off = 32; off > 0; off >>= 1) v += __shfl_down(v, off, 64);
    return __shfl(v, 0, 64);
}

// ---------------------------------------------------------------------------
// prep kernels for front2's folded LN: W2g[d,c] = kqv_w[d,c]*ln_g[d];
// S2[c] = sum_d W2g[d,c]; S3[c] = sum_d kqv_w[d,c]*ln_b[d] + kqv_b[c].
// ---------------------------------------------------------------------------
__global__ __launch_bounds__(256) void prep_scale(
    const float* __restrict__ w, const float* __restrict__ g,
    float* __restrict__ w2)
{
    const int i = blockIdx.x * 256 + threadIdx.x;
    if (i < D2 * 192) w2[i] = w[i] * g[i / 192];
}

__global__ __launch_bounds__(192) void prep_sums(
    const float* __restrict__ w, const float* __restrict__ g,
    const float* __restrict__ bb, const float* __restrict__ kqvb,
    float* __restrict__ s2, float* __restrict__ s3)
{
    const int col = threadIdx.x;
    float a2 = 0.f, a3 = 0.f;
    for (int d = 0; d < D2; ++d) {
        const float wv = w[d * 192 + col];
        a2 += wv * g[d];
        a3 += wv * bb[d];
    }
    s2[col] = a2; s3[col] = a3 + kqvb[col];
}

// ---------------------------------------------------------------------------
// front1: 32 tokens/block, 256 threads. unfold(7,4,2) + LN + kqv + prm_exp.
// R8 structure; rf load moved AFTER matvec (frees 64 VGPRs in hot loop).
// ---------------------------------------------------------------------------
__global__ __launch_bounds__(256) void front1(
    const float* __restrict__ x,
    const float* __restrict__ kqv_w,   // (147,192)
    const float* __restrict__ kqv_b,   // (192)
    const float* __restrict__ ln_g, const float* __restrict__ ln_b,  // (147)
    const float* __restrict__ rf,      // (32,64)
    float* __restrict__ kp, float* __restrict__ qp,   // (B*T1,32)
    float* __restrict__ v_out)                        // (B*T1,64)
{
    const int tok0 = blockIdx.x * 32;
    const int b = tok0 / T1;
    const int tbase = tok0 % T1;
    const int tid = threadIdx.x;
    const int c = tid & 63, tg = tid >> 6;
    const int lane = tid & 63;

    __shared__ __align__(16) float smem[D1 * 36];
    __shared__ float ps_sum[256], ps_sq[256];
    __shared__ float mu_s[32], rs_s[32];
    __shared__ float xd_s[64];

    float* ft  = smem;
    float* kqs = smem;

    for (int idx = tid; idx < D1 * 32; idx += 256) {
        const int m = idx & 31, d = idx >> 5;
        const int t = tbase + m;
        const int py = t / 56, px = t % 56;
        const int cc = d / 49, r = d % 49, ki = r / 7, kj = r % 7;
        const int iy = py * 4 - 2 + ki, ix = px * 4 - 2 + kj;
        float val = 0.f;
        if (iy >= 0 && iy < 224 && ix >= 0 && ix < 224)
            val = x[((b * 3 + cc) * 224 + iy) * 224 + ix];
        ft[d * 36 + m] = val;
    }
    __syncthreads();

    { const int m = tid & 31, j = tid >> 5;
      float s = 0.f, s2 = 0.f;
      for (int d = j; d < D1; d += 8) { const float u = ft[d*36+m]; s += u; s2 += u*u; }
      ps_sum[tid] = s; ps_sq[tid] = s2; }
    __syncthreads();
    if (tid < 32) {
        float s = 0.f, s2 = 0.f;
        for (int j = 0; j < 8; ++j) { s += ps_sum[j*32+tid]; s2 += ps_sq[j*32+tid]; }
        const float mu = s * (1.f / D1);
        const float var = s2 * (1.f / D1) - mu * mu;
        mu_s[tid] = mu; rs_s[tid] = rsqrtf(var + 1e-5f);
    }
    __syncthreads();
    for (int idx = tid; idx < D1 * 32; idx += 256) {
        const int m = idx & 31, d = idx >> 5;
        ft[d*36+m] = (ft[d*36+m] - mu_s[m]) * rs_s[m] * ln_g[d] + ln_b[d];
    }
    __syncthreads();

    float acc[3][8];
    { const float b0 = kqv_b[c], b1 = kqv_b[64 + c], b2 = kqv_b[128 + c];
#pragma unroll
      for (int m = 0; m < 8; ++m) { acc[0][m] = b0; acc[1][m] = b1; acc[2][m] = b2; } }

    float w0[3], w1[3], w2[3], n0[3], n1[3], n2[3];
    { const float* wp = kqv_w + c;
#pragma unroll
      for (int i = 0; i < 3; ++i) { w0[i] = wp[i*192]; w1[i] = wp[i*192+64]; w2[i] = wp[i*192+128]; } }
    for (int dg = 0; dg < 49; ++dg) {
        if (dg < 48) {
            const float* wp = kqv_w + (dg * 3 + 3) * 192 + c;
#pragma unroll
            for (int i = 0; i < 3; ++i) { n0[i] = wp[i*192]; n1[i] = wp[i*192+64]; n2[i] = wp[i*192+128]; }
        }
#pragma unroll
        for (int i = 0; i < 3; ++i) {
            const int d = dg * 3 + i;
            const float4 f0 = *(const float4*)&ft[d * 36 + 8 * tg];
            const float4 f1 = *(const float4*)&ft[d * 36 + 8 * tg + 4];
            acc[0][0] += f0.x*w0[i]; acc[0][1] += f0.y*w0[i]; acc[0][2] += f0.z*w0[i]; acc[0][3] += f0.w*w0[i];
            acc[0][4] += f1.x*w0[i]; acc[0][5] += f1.y*w0[i]; acc[0][6] += f1.z*w0[i]; acc[0][7] += f1.w*w0[i];
            acc[1][0] += f0.x*w1[i]; acc[1][1] += f0.y*w1[i]; acc[1][2] += f0.z*w1[i]; acc[1][3] += f0.w*w1[i];
            acc[1][4] += f1.x*w1[i]; acc[1][5] += f1.y*w1[i]; acc[1][6] += f1.z*w1[i]; acc[1][7] += f1.w*w1[i];
            acc[2][0] += f0.x*w2[i]; acc[2][1] += f0.y*w2[i]; acc[2][2] += f0.z*w2[i]; acc[2][3] += f0.w*w2[i];
            acc[2][4] += f1.x*w2[i]; acc[2][5] += f1.y*w2[i]; acc[2][6] += f1.z*w2[i]; acc[2][7] += f1.w*w2[i];
        }
#pragma unroll
        for (int i = 0; i < 3; ++i) { w0[i] = n0[i]; w1[i] = n1[i]; w2[i] = n2[i]; }
    }
    __syncthreads();

#pragma unroll
    for (int m = 0; m < 8; ++m)
        v_out[(size_t)(tok0 + 8 * tg + m) * 64 + c] = acc[2][m];
#pragma unroll
    for (int m = 0; m < 8; ++m) {
        kqs[(0 * 32 + 8 * tg + m) * 64 + c] = acc[0][m];
        kqs[(1 * 32 + 8 * tg + m) * 64 + c] = acc[1][m];
    }
#pragma unroll
    for (int m = 0; m < 8; ++m) {
        const float sk = waveReduceSum(acc[0][m] * acc[0][m]);
        const float sq = waveReduceSum(acc[1][m] * acc[1][m]);
        if (lane == 0) { xd_s[8 * tg + m] = 0.5f * sk; xd_s[32 + 8 * tg + m] = 0.5f * sq; }
    }
    __syncthreads();

    float4 rfr[16];
    { const float* rp = rf + (size_t)(tid & 31) * 64;
#pragma unroll
      for (int g = 0; g < 16; ++g) rfr[g] = *(const float4*)(rp + 4 * g); }

    for (int slot = tid; slot < 2048; slot += 256) {
        const int half = slot >> 10, rem = slot & 1023;
        const int m = rem >> 5, mrf = slot & 31;
        const float4* k4 = (const float4*)&kqs[(half * 32 + m) * 64];
        float a = 0.f;
#pragma unroll
        for (int g = 0; g < 16; ++g) {
            const float4 kv = k4[g];
            a += rfr[g].x*kv.x + rfr[g].y*kv.y + rfr[g].z*kv.z + rfr[g].w*kv.w;
        }
        const float p = expf(a - xd_s[half * 32 + m]) * 0.1767766952966369f;
        (half ? qp : kp)[(size_t)(tok0 + m) * 32 + mrf] = p;
    }
}

// ---------------------------------------------------------------------------
// front2: 16 tokens/block, 128 threads. Chunk-streamed (4 x 144-row chunks,
// double-buffered, ~24KB LDS -> 6 blocks/CU) with LN folded out of the matvec
// via pre-scaled weights (W2g, S2, S3). Matvec runs on RAW unfold values;
// per-token (mu, rs) correction applied at the end.
// ---------------------------------------------------------------------------
__global__ __launch_bounds__(128) void front2(
    const float* __restrict__ src,     // o1 (B*T1,64)
    const float* __restrict__ w2g,     // (576,192) pre-scaled
    const float* __restrict__ s2v,     // (192)
    const float* __restrict__ s3v,     // (192)
    const float* __restrict__ rf,
    float* __restrict__ kp, float* __restrict__ qp,   // (B*T2,32)
    float* __restrict__ v_out)                        // (B*T2,64)
{
    const int tok0 = blockIdx.x * 16;
    const int b = tok0 / T2;
    const int tbase = tok0 % T2;   // T2 % 16 == 0
    const int tid = threadIdx.x;
    const int c = tid & 63, tg = tid >> 6;
    const int lane = tid & 63;
    const int cl = tid & 15, grp = tid >> 4;     // fill mapping (16 ch x 8 grp)

    __shared__ __align__(16) float buf[2][144 * 20];  // 23KB double buffer
    __shared__ float ps_sum[128], ps_sq[128];
    __shared__ float mu_s[16], rs_s[16];
    __shared__ float xd_s[32];

    float* kqs = &buf[0][0];    // [2][16][64] = 2048 floats, aliases buf0

    float acc[3][8];
#pragma unroll
    for (int i = 0; i < 3; ++i)
#pragma unroll
        for (int m = 0; m < 8; ++m) acc[i][m] = 0.f;   // bias folded into S3
    float sm = 0.f, sq = 0.f;                           // LN partials

    // --- prologue: fill chunk 0 (channels 0..15) ---
#pragma unroll
    for (int ii = 0; ii < 18; ++ii) {
        const int u = grp + ii * 8;          // u = m*9 + r, covers [0,144)
        const int m = u / 9, r = u % 9;
        const int t = tbase + m;
        const int py = t / 28, px = t % 28;
        const int iy = py * 2 - 1 + r / 3, ix = px * 2 - 1 + r % 3;
        float val = 0.f;
        if (iy >= 0 && iy < 56 && ix >= 0 && ix < 56)
            val = src[(size_t)(b * T1 + iy * 56 + ix) * 64 + cl];
        buf[0][(cl * 9 + r) * 20 + m] = val;
    }
    __syncthreads();

    // weight prologue: rows 0..3
    float w0[4], w1[4], w2[4];
    { const float* wp = w2g + c;
#pragma unroll
      for (int i = 0; i < 4; ++i) { w0[i] = wp[i*192]; w1[i] = wp[i*192+64]; w2[i] = wp[i*192+128]; } }

    for (int k = 0; k < 4; ++k) {
        // issue next chunk's fill loads into registers (hidden behind FMAs)
        float fv[18];
        if (k < 3) {
            const int c0 = (k + 1) * 16;
#pragma unroll
            for (int ii = 0; ii < 18; ++ii) {
                const int u = grp + ii * 8;
                const int m = u / 9, r = u % 9;
                const int t = tbase + m;
                const int py = t / 28, px = t % 28;
                const int iy = py * 2 - 1 + r / 3, ix = px * 2 - 1 + r % 3;
                float val = 0.f;
                if (iy >= 0 && iy < 56 && ix >= 0 && ix < 56)
                    val = src[(size_t)(b * T1 + iy * 56 + ix) * 64 + c0 + cl];
                fv[ii] = val;
            }
        }

        const float* bufk = buf[k & 1];
        for (int dg = 0; dg < 36; ++dg) {
            const int grow = k * 144 + dg * 4;
            float n0[4], n1[4], n2[4];
            if (grow + 4 < D2) {
                const float* wp = w2g + (size_t)(grow + 4) * 192 + c;
#pragma unroll
                for (int i = 0; i < 4; ++i) { n0[i] = wp[i*192]; n1[i] = wp[i*192+64]; n2[i] = wp[i*192+128]; }
            }
#pragma unroll
            for (int i = 0; i < 4; ++i) {
                const int dl = dg * 4 + i;
                const float4 f0 = *(const float4*)&bufk[dl * 20 + 8 * tg];
                const float4 f1 = *(const float4*)&bufk[dl * 20 + 8 * tg + 4];
                acc[0][0] += f0.x*w0[i]; acc[0][1] += f0.y*w0[i]; acc[0][2] += f0.z*w0[i]; acc[0][3] += f0.w*w0[i];
                acc[0][4] += f1.x*w0[i]; acc[0][5] += f1.y*w0[i]; acc[0][6] += f1.z*w0[i]; acc[0][7] += f1.w*w0[i];
                acc[1][0] += f0.x*w1[i]; acc[1][1] += f0.y*w1[i]; acc[1][2] += f0.z*w1[i]; acc[1][3] += f0.w*w1[i];
                acc[1][4] += f1.x*w1[i]; acc[1][5] += f1.y*w1[i]; acc[1][6] += f1.z*w1[i]; acc[1][7] += f1.w*w1[i];
                acc[2][0] += f0.x*w2[i]; acc[2][1] += f0.y*w2[i]; acc[2][2] += f0.z*w2[i]; acc[2][3] += f0.w*w2[i];
                acc[2][4] += f1.x*w2[i]; acc[2][5] += f1.y*w2[i]; acc[2][6] += f1.z*w2[i]; acc[2][7] += f1.w*w2[i];
            }
#pragma unroll
            for (int i = 0; i < 4; ++i) { w0[i] = n0[i]; w1[i] = n1[i]; w2[i] = n2[i]; }
        }

        // LN stats on this chunk: token mm = tid&15, group grp over d_local
        { const int mm = tid & 15, j = tid >> 4;
          for (int dl = j; dl < 144; dl += 8) {
              const float u = bufk[dl * 20 + mm];
              sm += u; sq += u * u;
          } }

        // commit next chunk's fill to the other buffer
        if (k < 3) {
            float* bufn = buf[(k + 1) & 1];
#pragma unroll
            for (int ii = 0; ii < 18; ++ii) {
                const int u = grp + ii * 8;
                bufn[(cl * 9 + u % 9) * 20 + u / 9] = fv[ii];
            }
        }
        __syncthreads();
    }

    // reduce LN stats
    ps_sum[tid] = sm; ps_sq[tid] = sq;
    __syncthreads();
    if (tid < 16) {
        float s = 0.f, s2 = 0.f;
        for (int j = 0; j < 8; ++j) { s += ps_sum[j*16+tid]; s2 += ps_sq[j*16+tid]; }
        const float mu = s * (1.f / D2);
        const float var = s2 * (1.f / D2) - mu * mu;
        mu_s[tid] = mu; rs_s[tid] = rsqrtf(var + 1e-5f);
    }
    __syncthreads();

    // fold-correction: out = rs*(acc - mu*S2) + S3
    { float s2c[3], s3c[3];
#pragma unroll
      for (int i = 0; i < 3; ++i) { s2c[i] = s2v[c + 64*i]; s3c[i] = s3v[c + 64*i]; }
#pragma unroll
      for (int m = 0; m < 8; ++m) {
          const int tm = 8 * tg + m;
          const float mu = mu_s[tm], rs = rs_s[tm];
#pragma unroll
          for (int i = 0; i < 3; ++i)
              acc[i][m] = rs * (acc[i][m] - mu * s2c[i]) + s3c[i];
      } }

#pragma unroll
    for (int m = 0; m < 8; ++m)
        v_out[(size_t)(tok0 + 8 * tg + m) * 64 + c] = acc[2][m];
#pragma unroll
    for (int m = 0; m < 8; ++m) {
        kqs[(0 * 16 + 8 * tg + m) * 64 + c] = acc[0][m];
        kqs[(1 * 16 + 8 * tg + m) * 64 + c] = acc[1][m];
    }
#pragma unroll
    for (int m = 0; m < 8; ++m) {
        const float sk = waveReduceSum(acc[0][m] * acc[0][m]);
        const float sq2 = waveReduceSum(acc[1][m] * acc[1][m]);
        if (lane == 0) { xd_s[8 * tg + m] = 0.5f * sk; xd_s[16 + 8 * tg + m] = 0.5f * sq2; }
    }
    __syncthreads();

    float4 rfr[16];
    { const float* rp = rf + (size_t)(tid & 31) * 64;
#pragma unroll
      for (int g = 0; g < 16; ++g) rfr[g] = *(const float4*)(rp + 4 * g); }

    for (int slot = tid; slot < 1024; slot += 128) {
        const int half = slot >> 9, rem = slot & 511;
        const int m = rem >> 5, mrf = slot & 31;
        const float4* k4 = (const float4*)&kqs[(half * 16 + m) * 64];
        float a = 0.f;
#pragma unroll
        for (int g = 0; g < 16; ++g) {
            const float4 kv = k4[g];
            a += rfr[g].x*kv.x + rfr[g].y*kv.y + rfr[g].z*kv.z + rfr[g].w*kv.w;
        }
        const float p = expf(a - xd_s[half * 16 + m]) * 0.1767766952966369f;
        (half ? qp : kp)[(size_t)(tok0 + m) * 32 + mrf] = p;
    }
}

// ---------------------------------------------------------------------------
// reduce_kv, split S-ways over T with atomics (ksum/kptv pre-zeroed)
// ---------------------------------------------------------------------------
template <int T, int S>
__global__ __launch_bounds__(256) void reduce_kv(
    const float* __restrict__ kp, const float* __restrict__ v,
    float* __restrict__ ksum, float* __restrict__ kptv)
{
    const int b = blockIdx.x / S, s = blockIdx.x % S;
    const int chunk = T / S;
    const int tid = threadIdx.x;
    __shared__ float kp_s[8][32];
    __shared__ float v_s[8][64];
    float acc[8] = {0.f, 0.f, 0.f, 0.f, 0.f, 0.f, 0.f, 0.f};
    float ks = 0.f;
    const int n = tid >> 2;
    const int mb = (tid & 3) * 8;
    const float* kpb = kp + (size_t)b * T * 32;
    const float* vb  = v  + (size_t)b * T * 64;

    for (int t0 = s * chunk; t0 < (s + 1) * chunk; t0 += 8) {
        kp_s[tid >> 5][tid & 31] = kpb[(t0 + (tid >> 5)) * 32 + (tid & 31)];
        {
            const int i0 = tid * 2, i1 = tid * 2 + 1;
            v_s[i0 >> 6][i0 & 63] = vb[(t0 + (i0 >> 6)) * 64 + (i0 & 63)];
            v_s[i1 >> 6][i1 & 63] = vb[(t0 + (i1 >> 6)) * 64 + (i1 & 63)];
        }
        __syncthreads();
#pragma unroll
        for (int tt = 0; tt < 8; ++tt) {
            const float vv = v_s[tt][n];
#pragma unroll
            for (int i = 0; i < 8; ++i) acc[i] += vv * kp_s[tt][mb + i];
        }
        if (tid < 32) {
#pragma unroll
            for (int tt = 0; tt < 8; ++tt) ks += kp_s[tt][tid];
        }
        __syncthreads();
    }
#pragma unroll
    for (int i = 0; i < 8; ++i) atomicAdd(&kptv[(b * 64 + n) * 32 + mb + i], acc[i]);
    if (tid < 32) atomicAdd(&ksum[b * 32 + tid], ks);
}

// ---------------------------------------------------------------------------
// epilogue: 128 threads = two independent 16-token tiles; per-sub ksum.
// ---------------------------------------------------------------------------
template <int T>
__global__ __launch_bounds__(128) void epilogue(
    const float* __restrict__ qp, const float* __restrict__ v,
    const float* __restrict__ ksum, const float* __restrict__ kptv,
    const float* __restrict__ proj_w, const float* __restrict__ proj_b,
    const float* __restrict__ ln2_g, const float* __restrict__ ln2_b,
    const float* __restrict__ m1_w, const float* __restrict__ m1_b,
    const float* __restrict__ m2_w, const float* __restrict__ m2_b,
    float* __restrict__ out)
{
    const int sub = threadIdx.x >> 6;
    const int e = threadIdx.x & 63;
    const int tok0 = blockIdx.x * 32 + sub * 16;
    const int b = tok0 / T;

    __shared__ __align__(16) float qp_s[2][16 * 36];
    __shared__ __align__(16) float buf[2][64 * 20];
    __shared__ float ks_s[2][32];
    __shared__ float D_s[2][16];

    for (int idx = e; idx < 512; idx += 64)
        qp_s[sub][(idx >> 5) * 36 + (idx & 31)] = qp[(size_t)tok0 * 32 + idx];
    if (e < 32) ks_s[sub][e] = ksum[b * 32 + e];
    __syncthreads();
    if (e < 16) {
        float D = 1e-8f;
        for (int r = 0; r < 32; ++r) D += qp_s[sub][e * 36 + r] * ks_s[sub][r];
        D_s[sub][e] = D;
    }
    float4 kv4[8];
#pragma unroll
    for (int g = 0; g < 8; ++g)
        kv4[g] = *(const float4*)&kptv[(size_t)(b * 64 + e) * 32 + 4 * g];
    __syncthreads();

    float ya[16];
#pragma unroll
    for (int m = 0; m < 16; ++m) {
        const float4* q4 = (const float4*)&qp_s[sub][m * 36];
        float a = 0.f;
#pragma unroll
        for (int g = 0; g < 8; ++g) {
            const float4 qv = q4[g];
            a += qv.x*kv4[g].x + qv.y*kv4[g].y + qv.z*kv4[g].z + qv.w*kv4[g].w;
        }
        ya[m] = a / D_s[sub][m];
    }
#pragma unroll
    for (int g = 0; g < 4; ++g)
        *(float4*)&buf[sub][e * 20 + 4*g] = make_float4(ya[4*g], ya[4*g+1], ya[4*g+2], ya[4*g+3]);
    __syncthreads();

    float y[16];
    { float acc2[16];
      const float pb = proj_b[e];
#pragma unroll
      for (int m = 0; m < 16; ++m) acc2[m] = pb;
      for (int j = 0; j < 64; ++j) {
          const float w = proj_w[j * 64 + e];
          const float4* a4 = (const float4*)&buf[sub][j * 20];
#pragma unroll
          for (int g = 0; g < 4; ++g) {
              const float4 av = a4[g];
              acc2[4*g+0] += av.x * w; acc2[4*g+1] += av.y * w;
              acc2[4*g+2] += av.z * w; acc2[4*g+3] += av.w * w;
          }
      }
#pragma unroll
      for (int m = 0; m < 16; ++m)
          y[m] = v[(size_t)(tok0 + m) * 64 + e] + acc2[m];
    }
    __syncthreads();

    { const float g2 = ln2_g[e], bb = ln2_b[e];
      float z[16];
#pragma unroll
      for (int m = 0; m < 16; ++m) {
          const float s  = waveReduceSum(y[m]);
          const float s2 = waveReduceSum(y[m] * y[m]);
          const float mu = s * (1.f / 64.f);
          const float var = s2 * (1.f / 64.f) - mu * mu;
          z[m] = (y[m] - mu) * rsqrtf(var + 1e-5f) * g2 + bb;
      }
#pragma unroll
      for (int g = 0; g < 4; ++g)
          *(float4*)&buf[sub][e * 20 + 4*g] = make_float4(z[4*g], z[4*g+1], z[4*g+2], z[4*g+3]);
    }
    __syncthreads();

    float h[16];
    { const float b1 = m1_b[e];
#pragma unroll
      for (int m = 0; m < 16; ++m) h[m] = b1;
      for (int j = 0; j < 64; ++j) {
          const float w = m1_w[j * 64 + e];
          const float4* a4 = (const float4*)&buf[sub][j * 20];
#pragma unroll
          for (int g = 0; g < 4; ++g) {
              const float4 av = a4[g];
              h[4*g+0] += av.x * w; h[4*g+1] += av.y * w;
              h[4*g+2] += av.z * w; h[4*g+3] += av.w * w;
          }
      }
#pragma unroll
      for (int m = 0; m < 16; ++m)
          h[m] = 0.5f * h[m] * (1.f + erff(h[m] * 0.7071067811865476f));
    }
    __syncthreads();
#pragma unroll
    for (int g = 0; g < 4; ++g)
        *(float4*)&buf[sub][e * 20 + 4*g] = make_float4(h[4*g], h[4*g+1], h[4*g+2], h[4*g+3]);
    __syncthreads();

    { const float b2v = m2_b[e];
      float acc4[16];
#pragma unroll
      for (int m = 0; m < 16; ++m) acc4[m] = b2v;
      for (int j = 0; j < 64; ++j) {
          const float w = m2_w[j * 64 + e];
          const float4* a4 = (const float4*)&buf[sub][j * 20];
#pragma unroll
          for (int g = 0; g < 4; ++g) {
              const float4 av = a4[g];
              acc4[4*g+0] += av.x * w; acc4[4*g+1] += av.y * w;
              acc4[4*g+2] += av.z * w; acc4[4*g+3] += av.w * w;
          }
      }
#pragma unroll
      for (int m = 0; m < 16; ++m)
          out[(size_t)(tok0 + m) * 64 + e] = y[m] + acc4[m];
    }
}

// ---------------------------------------------------------------------------
// final: unfold(3,2,1) from o2 + dense 576->768. 16 tokens/block, 256 threads.
// Chunk-streamed (4 x 144-row chunks, double-buffered, ~23KB LDS).
// ---------------------------------------------------------------------------
__global__ __launch_bounds__(256) void final_proj(
    const float* __restrict__ o2,    // (B*T2,64)
    const float* __restrict__ w,     // (576,768)
    const float* __restrict__ bias,  // (768)
    float* __restrict__ out)         // (B*T3,768)
{
    const int tok0 = blockIdx.x * 16;
    const int tid = threadIdx.x;
    const int cl = tid & 15, grp = tid >> 4;   // 16 ch x 16 grp

    __shared__ __align__(16) float buf[2][144 * 20];

    float acc[3][16];
    { const float b0 = bias[tid], b1 = bias[tid + 256], b2 = bias[tid + 512];
#pragma unroll
      for (int m = 0; m < 16; ++m) { acc[0][m] = b0; acc[1][m] = b1; acc[2][m] = b2; } }

    // prologue fill chunk 0
#pragma unroll
    for (int ii = 0; ii < 9; ++ii) {
        const int u = grp + ii * 16;         // m*9 + r
        const int m = u / 9, r = u % 9;
        const int tok = tok0 + m, bb = tok / T3, tt = tok % T3;
        const int py = tt / 14, px = tt % 14;
        const int iy = py * 2 - 1 + r / 3, ix = px * 2 - 1 + r % 3;
        float val = 0.f;
        if (iy >= 0 && iy < 28 && ix >= 0 && ix < 28)
            val = o2[(size_t)(bb * T2 + iy * 28 + ix) * 64 + cl];
        buf[0][(cl * 9 + r) * 20 + m] = val;
    }
    __syncthreads();

    float w0[4], w1[4], w2[4];
    { const float* wp = w + tid;
#pragma unroll
      for (int i = 0; i < 4; ++i) { w0[i] = wp[i*768]; w1[i] = wp[i*768+256]; w2[i] = wp[i*768+512]; } }

    for (int k = 0; k < 4; ++k) {
        float fv[9];
        if (k < 3) {
            const int c0 = (k + 1) * 16;
#pragma unroll
            for (int ii = 0; ii < 9; ++ii) {
                const int u = grp + ii * 16;
                const int m = u / 9, r = u % 9;
                const int tok = tok0 + m, bb = tok / T3, tt = tok % T3;
                const int py = tt / 14, px = tt % 14;
                const int iy = py * 2 - 1 + r / 3, ix = px * 2 - 1 + r % 3;
                float val = 0.f;
                if (iy >= 0 && iy < 28 && ix >= 0 && ix < 28)
                    val = o2[(size_t)(bb * T2 + iy * 28 + ix) * 64 + c0 + cl];
                fv[ii] = val;
            }
        }

        const float* bufk = buf[k & 1];
        for (int dg = 0; dg < 36; ++dg) {
            const int grow = k * 144 + dg * 4;
            float n0[4], n1[4], n2[4];
            if (grow + 4 < D2) {
                const float* wp = w + (size_t)(grow + 4) * 768 + tid;
#pragma unroll
                for (int i = 0; i < 4; ++i) { n0[i] = wp[i*768]; n1[i] = wp[i*768+256]; n2[i] = wp[i*768+512]; }
            }
#pragma unroll
            for (int i = 0; i < 4; ++i) {
                const int dl = dg * 4 + i;
                const float4* f4 = (const float4*)&bufk[dl * 20];
#pragma unroll
                for (int g = 0; g < 4; ++g) {
                    const float4 f = f4[g];
                    acc[0][4*g+0] += f.x * w0[i]; acc[0][4*g+1] += f.y * w0[i];
                    acc[0][4*g+2] += f.z * w0[i]; acc[0][4*g+3] += f.w * w0[i];
                    acc[1][4*g+0] += f.x * w1[i]; acc[1][4*g+1] += f.y * w1[i];
                    acc[1][4*g+2] += f.z * w1[i]; acc[1][4*g+3] += f.w * w1[i];
                    acc[2][4*g+0] += f.x * w2[i]; acc[2][4*g+1] += f.y * w2[i];
                    acc[2][4*g+2] += f.z * w2[i]; acc[2][4*g+3] += f.w * w2[i];
                }
            }
#pragma unroll
            for (int i = 0; i < 4; ++i) { w0[i] = n0[i]; w1[i] = n1[i]; w2[i] = n2[i]; }
        }

        if (k < 3) {
            float* bufn = buf[(k + 1) & 1];
#pragma unroll
            for (int ii = 0; ii < 9; ++ii) {
                const int u = grp + ii * 16;
                bufn[(cl * 9 + u % 9) * 20 + u / 9] = fv[ii];
            }
        }
        __syncthreads();
    }

#pragma unroll
    for (int m = 0; m < 16; ++m) {
        const size_t ob = (size_t)(tok0 + m) * 768 + tid;
        out[ob]       = acc[0][m];
        out[ob + 256] = acc[1][m];
        out[ob + 512] = acc[2][m];
    }
}

// ---------------------------------------------------------------------------
extern "C" void kernel_launch(void* const* d_in, const int* in_sizes, int n_in,
                              void* d_out, int out_size, void* d_ws, size_t ws_size,
                              hipStream_t stream) {
    const float* x         = (const float*)d_in[0];
    const float* p1_kqv_w  = (const float*)d_in[1];
    const float* p1_kqv_b  = (const float*)d_in[2];
    const float* p1_proj_w = (const float*)d_in[3];
    const float* p1_proj_b = (const float*)d_in[4];
    const float* p1_ln1_g  = (const float*)d_in[5];
    const float* p1_ln1_b  = (const float*)d_in[6];
    const float* p1_ln2_g  = (const float*)d_in[7];
    const float* p1_ln2_b  = (const float*)d_in[8];
    const float* p1_m1_w   = (const float*)d_in[9];
    const float* p1_m1_b   = (const float*)d_in[10];
    const float* p1_m2_w   = (const float*)d_in[11];
    const float* p1_m2_b   = (const float*)d_in[12];
    const float* p1_rf     = (const float*)d_in[13];
    const float* p2_kqv_w  = (const float*)d_in[14];
    const float* p2_kqv_b  = (const float*)d_in[15];
    const float* p2_proj_w = (const float*)d_in[16];
    const float* p2_proj_b = (const float*)d_in[17];
    const float* p2_ln1_g  = (const float*)d_in[18];
    const float* p2_ln1_b  = (const float*)d_in[19];
    const float* p2_ln2_g  = (const float*)d_in[20];
    const float* p2_ln2_b  = (const float*)d_in[21];
    const float* p2_m1_w   = (const float*)d_in[22];
    const float* p2_m1_b   = (const float*)d_in[23];
    const float* p2_m2_w   = (const float*)d_in[24];
    const float* p2_m2_b   = (const float*)d_in[25];
    const float* p2_rf     = (const float*)d_in[26];
    const float* proj_w    = (const float*)d_in[27];
    const float* proj_b    = (const float*)d_in[28];

    float* ws = (float*)d_ws;
    size_t off = 0;
    float* ksum1 = ws + off; off += (size_t)NB * 32;
    float* kptv1 = ws + off; off += (size_t)NB * 64 * 32;
    float* ksum2 = ws + off; off += (size_t)NB * 32;
    float* kptv2 = ws + off; off += (size_t)NB * 64 * 32;
    const size_t zero_bytes = off * sizeof(float);
    float* kp1 = ws + off; off += (size_t)NB * T1 * 32;
    float* qp1 = ws + off; off += (size_t)NB * T1 * 32;
    float* v1  = ws + off; off += (size_t)NB * T1 * 64;
    float* o1  = ws + off; off += (size_t)NB * T1 * 64;
    float* w2g = ws + off; off += (size_t)D2 * 192;
    float* s2v = ws + off; off += 192;
    float* s3v = ws + off; off += 192;
    size_t off2 = 0;
    float* kp2 = kp1 + off2; off2 += (size_t)NB * T2 * 32;
    float* qp2 = kp1 + off2; off2 += (size_t)NB * T2 * 32;
    float* v2  = kp1 + off2; off2 += (size_t)NB * T2 * 64;
    float* o2  = kp1 + off2; off2 += (size_t)NB * T2 * 64;

    hipMemsetAsync(ws, 0, zero_bytes, stream);

    prep_scale<<<(D2 * 192 + 255) / 256, 256, 0, stream>>>(p2_kqv_w, p2_ln1_g, w2g);
    prep_sums<<<1, 192, 0, stream>>>(p2_kqv_w, p2_ln1_g, p2_ln1_b, p2_kqv_b, s2v, s3v);

    front1<<<NB * T1 / 32, 256, 0, stream>>>(x, p1_kqv_w, p1_kqv_b, p1_ln1_g,
                                             p1_ln1_b, p1_rf, kp1, qp1, v1);
    reduce_kv<T1, 14><<<NB * 14, 256, 0, stream>>>(kp1, v1, ksum1, kptv1);
    epilogue<T1><<<NB * T1 / 32, 128, 0, stream>>>(qp1, v1, ksum1, kptv1,
                                                   p1_proj_w, p1_proj_b, p1_ln2_g, p1_ln2_b,
                                                   p1_m1_w, p1_m1_b, p1_m2_w, p1_m2_b, o1);
    front2<<<NB * T2 / 16, 128, 0, stream>>>(o1, w2g, s2v, s3v, p2_rf, kp2, qp2, v2);
    reduce_kv<T2, 7><<<NB * 7, 256, 0, stream>>>(kp2, v2, ksum2, kptv2);
    epilogue<T2><<<NB * T2 / 32, 128, 0, stream>>>(qp2, v2, ksum2, kptv2,
                                                   p2_proj_w, p2_proj_b, p2_ln2_g, p2_ln2_b,
                                                   p2_m1_w, p2_m1_b, p2_m2_w, p2_m2_b, o2);
    final_proj<<<NB * T3 / 16, 256, 0, stream>>>(o2, proj_w, proj_b, (float*)d_out);
}